// Round 3
// baseline (1194.330 us; speedup 1.0000x reference)
//
#include <hip/hip_runtime.h>
#include <stdint.h>

typedef unsigned short u16;
typedef __attribute__((ext_vector_type(8))) short bf16x8;
typedef __attribute__((ext_vector_type(4))) float f32x4;

#define E_ 8
#define D_ 1024
#define DFF_ 4096
#define NTOK 8192
#define NA 16384
#define MAXROWS 17408
#define MAXTILES 136
#define LN_EPS 1e-5f

__device__ __forceinline__ u16 f2bf(float f) {
  union { float f; uint32_t u; } a; a.f = f;
  uint32_t r = a.u + 0x7FFFu + ((a.u >> 16) & 1u);
  return (u16)(r >> 16);
}
__device__ __forceinline__ float bf2f(u16 h) {
  union { uint32_t u; float f; } a; a.u = ((uint32_t)h) << 16; return a.f;
}

__device__ __forceinline__ void gload16(const void* g, void* l) {
  __builtin_amdgcn_global_load_lds((const __attribute__((address_space(1))) void*)g,
                                   (__attribute__((address_space(3))) void*)l, 16, 0, 0);
}

// block-wide mean/var over 1024 elements (256 threads x 4 each)
__device__ __forceinline__ void blockmv(float s, float q, float2* sm, int tid,
                                        float& mean, float& var) {
#pragma unroll
  for (int o = 32; o > 0; o >>= 1) {
    s += __shfl_xor(s, o, 64);
    q += __shfl_xor(q, o, 64);
  }
  if ((tid & 63) == 0) sm[tid >> 6] = make_float2(s, q);
  __syncthreads();
  if (tid == 0) {
    float ts = 0.f, tq = 0.f;
#pragma unroll
    for (int i = 0; i < 4; ++i) { ts += sm[i].x; tq += sm[i].y; }
    sm[0] = make_float2(ts, tq);
  }
  __syncthreads();
  mean = sm[0].x * (1.f / 1024.f);
  var  = sm[0].y * (1.f / 1024.f) - mean * mean;
  __syncthreads();
}

// ---------------- kernel 1: per-token stats, x_norm bf16, routing weights, counts
__global__ __launch_bounds__(256)
void k_stats(const float* __restrict__ x, const float* __restrict__ ew,
             const int* __restrict__ idx, const float* __restrict__ capu,
             const float* __restrict__ cap, u16* __restrict__ xn,
             float* __restrict__ wf, int* __restrict__ cnt) {
  __shared__ float2 sm[4];
  int t = blockIdx.x, tid = threadIdx.x;
  const float* xr = x + (size_t)t * D_;
  float v[4]; float s = 0.f, q = 0.f;
#pragma unroll
  for (int j = 0; j < 4; ++j) {
    v[j] = xr[tid + j * 256];
    s += v[j]; q += v[j] * v[j];
  }
  float m, var;
  blockmv(s, q, sm, tid, m, var);
  float rs = rsqrtf(var + LN_EPS);
#pragma unroll
  for (int j = 0; j < 4; ++j)
    xn[(size_t)t * D_ + tid + j * 256] = f2bf((v[j] - m) * rs);
  if (tid == 0) {
    float pw[2];
#pragma unroll
    for (int k = 0; k < 2; ++k) {
      int e = idx[t * 2 + k];
      float pen = capu[e] / (cap[e] + 1e-8f);
      pen = fminf(fmaxf(pen, 0.f), 2.f);
      pw[k] = ew[t * 2 + k] / (1.f + pen);
      atomicAdd(&cnt[e], 1);
    }
    float mx = fmaxf(pw[0], pw[1]);
    float z0 = expf(pw[0] - mx), z1 = expf(pw[1] - mx);
    float inv = 1.f / (z0 + z1);
    wf[t * 2] = z0 * inv; wf[t * 2 + 1] = z1 * inv;
  }
}

// ---------------- kernel 2: scan padded counts, tile->expert map
__global__ void k_scan(const int* __restrict__ cnt, int* __restrict__ offs,
                       int* __restrict__ tile_expert) {
  if (threadIdx.x == 0 && blockIdx.x == 0) {
    int o = 0;
    for (int e = 0; e < E_; ++e) {
      offs[e] = o;
      int p = (cnt[e] + 127) & ~127;
      for (int mtl = 0; mtl < (p >> 7); ++mtl) tile_expert[(o >> 7) + mtl] = e;
      o += p;
    }
    offs[E_] = o;
  }
}

// ---------------- kernel 3: assign rows
__global__ __launch_bounds__(256)
void k_assign(const int* __restrict__ idx, const int* __restrict__ offs,
              int* __restrict__ cnt2, int* __restrict__ rowmap,
              int* __restrict__ tok_of_row) {
  int i = blockIdx.x * 256 + threadIdx.x;
  if (i >= NA) return;
  int e = idx[i];
  int pos = atomicAdd(&cnt2[e], 1);
  int row = offs[e] + pos;
  rowmap[i] = row;
  tok_of_row[row] = i >> 1;
}

// ---------------- kernel 4: transpose+convert weights fp32->bf16, fold ln1_w, bias partials
// src [nmat][R][C] (expert stride e_step in source), dst [z][C][R]
// Vectorized: float4 loads (16B/lane), ushort4 stores (8B/lane).
__global__ __launch_bounds__(256)
void k_convert(const float* __restrict__ src, const float* __restrict__ lnw,
               const float* __restrict__ lnb, u16* __restrict__ dst,
               float* __restrict__ bias, int R, int C, int e_step) {
  __shared__ float tbuf[64][65];
  int z = blockIdx.z;
  int es = z * e_step;
  const float* s = src + (size_t)es * R * C;
  u16* dz = dst + (size_t)z * R * C;
  int r0 = blockIdx.y * 64, c0 = blockIdx.x * 64;
  int tid = threadIdx.x;
  // load: 4 passes; lane covers 4 consecutive cols (float4), 16 rows/pass
  int lr = tid >> 4;          // 0..15
  int lc4 = (tid & 15) * 4;   // 0,4,..,60
#pragma unroll
  for (int p = 0; p < 4; ++p) {
    int r = lr + p * 16;
    const float4 v = *(const float4*)&s[(size_t)(r0 + r) * C + (c0 + lc4)];
    tbuf[r][lc4 + 0] = v.x; tbuf[r][lc4 + 1] = v.y;
    tbuf[r][lc4 + 2] = v.z; tbuf[r][lc4 + 3] = v.w;
  }
  __syncthreads();
  if (bias != nullptr && tid < 64) {
    float acc = 0.f;
    const float* lb = lnb + (size_t)es * R;
#pragma unroll 8
    for (int r2 = 0; r2 < 64; ++r2) acc += lb[r0 + r2] * tbuf[r2][tid];
    atomicAdd(&bias[(size_t)z * C + c0 + tid], acc);
  }
  // write: lane owns fixed out-row (c) and 4 consecutive out-cols (r) -> ushort4
  int cw = tid >> 4;          // 0..15 (+16*p)
  int r4 = (tid & 15) * 4;    // 0,4,..,60
  float sv[4];
#pragma unroll
  for (int j = 0; j < 4; ++j)
    sv[j] = (lnw != nullptr) ? lnw[(size_t)es * R + r0 + r4 + j] : 1.f;
#pragma unroll
  for (int p = 0; p < 4; ++p) {
    int c = cw + p * 16;
    u16 o0 = f2bf(tbuf[r4 + 0][c] * sv[0]);
    u16 o1 = f2bf(tbuf[r4 + 1][c] * sv[1]);
    u16 o2 = f2bf(tbuf[r4 + 2][c] * sv[2]);
    u16 o3 = f2bf(tbuf[r4 + 3][c] * sv[3]);
    *(ushort4*)&dz[(size_t)(c0 + c) * R + (r0 + r4)] = make_ushort4(o0, o1, o2, o3);
  }
}

// ---------------- GEMM1, gelu/relu experts: h = act(x_norm @ w1t[e]^T + bias1[e])
__global__ __launch_bounds__(256, 3)
void gemm1_single(const u16* __restrict__ xn, const u16* __restrict__ w1t,
                  const float* __restrict__ bias1, const int* __restrict__ tok_of_row,
                  const int* __restrict__ tile_expert, u16* __restrict__ h) {
  int mtile = blockIdx.y;
  int e = tile_expert[mtile];
  if (e < 0 || (e % 3) == 0) return;
  int act = e % 3;  // 1=gelu, 2=relu
  int n0 = blockIdx.x * 128;
  int tid = threadIdx.x;
  int lane = tid & 63, wid = tid >> 6;
  int wm = wid & 1, wn = wid >> 1;

  __shared__ u16 As[128 * 64], Bs[128 * 64];
  __shared__ int stok[128];
  if (tid < 128) { int t = tok_of_row[mtile * 128 + tid]; stok[tid] = t < 0 ? 0 : t; }
  __syncthreads();

  const u16* pA[4]; const u16* pB[4];
#pragma unroll
  for (int i = 0; i < 4; ++i) {
    int r = i * 32 + (tid >> 3);
    int g = (tid & 7) ^ (r & 7);
    pA[i] = xn + (size_t)stok[r] * D_ + g * 8;
    pB[i] = w1t + ((size_t)e * DFF_ + n0 + r) * D_ + g * 8;
  }
  f32x4 acc[4][4];
#pragma unroll
  for (int mi = 0; mi < 4; ++mi)
#pragma unroll
    for (int ni = 0; ni < 4; ++ni) acc[mi][ni] = (f32x4){0.f, 0.f, 0.f, 0.f};

  for (int kk = 0; kk < D_; kk += 64) {
    if (kk) __syncthreads();
#pragma unroll
    for (int i = 0; i < 4; ++i) {
      gload16(pA[i], As + i * 2048 + wid * 512);
      gload16(pB[i], Bs + i * 2048 + wid * 512);
      pA[i] += 64; pB[i] += 64;
    }
    __syncthreads();
#pragma unroll
    for (int ks = 0; ks < 2; ++ks) {
      int slot = ((ks * 4) + (lane >> 4)) ^ (lane & 7);
      bf16x8 af[4], bfr[4];
#pragma unroll
      for (int mi = 0; mi < 4; ++mi)
        af[mi] = *(const bf16x8*)(As + (wm * 64 + mi * 16 + (lane & 15)) * 64 + slot * 8);
#pragma unroll
      for (int ni = 0; ni < 4; ++ni)
        bfr[ni] = *(const bf16x8*)(Bs + (wn * 64 + ni * 16 + (lane & 15)) * 64 + slot * 8);
#pragma unroll
      for (int mi = 0; mi < 4; ++mi)
#pragma unroll
        for (int ni = 0; ni < 4; ++ni)
          acc[mi][ni] = __builtin_amdgcn_mfma_f32_16x16x32_bf16(af[mi], bfr[ni], acc[mi][ni], 0, 0, 0);
    }
  }
  int quad = lane >> 4;
#pragma unroll
  for (int ni = 0; ni < 4; ++ni) {
    int col = n0 + wn * 64 + ni * 16 + (lane & 15);
    float b1 = bias1[(size_t)e * DFF_ + col];
#pragma unroll
    for (int mi = 0; mi < 4; ++mi) {
      int rowb = mtile * 128 + wm * 64 + mi * 16 + quad * 4;
#pragma unroll
      for (int r = 0; r < 4; ++r) {
        float v = acc[mi][ni][r] + b1;
        if (act == 1) v = 0.5f * v * (1.f + erff(v * 0.70710678118f));
        else v = fmaxf(v, 0.f);
        h[(size_t)(rowb + r) * DFF_ + col] = f2bf(v);
      }
    }
  }
}

// ---------------- GEMM1, swiglu experts: dual accumulate h1,h2; h = silu(h2)*h2*h1
__global__ __launch_bounds__(256, 2)
void gemm1_swiglu(const u16* __restrict__ xn, const u16* __restrict__ w1t,
                  const u16* __restrict__ w2t, const float* __restrict__ bias1,
                  const float* __restrict__ bias2, const int* __restrict__ tok_of_row,
                  const int* __restrict__ tile_expert, u16* __restrict__ h) {
  int mtile = blockIdx.y;
  int e = tile_expert[mtile];
  if (e < 0 || (e % 3) != 0) return;
  int se = e / 3;
  int n0 = blockIdx.x * 128;
  int tid = threadIdx.x;
  int lane = tid & 63, wid = tid >> 6;
  int wm = wid & 1, wn = wid >> 1;

  __shared__ u16 As[128 * 64], Bs[128 * 64], Cs[128 * 64];
  __shared__ int stok[128];
  if (tid < 128) { int t = tok_of_row[mtile * 128 + tid]; stok[tid] = t < 0 ? 0 : t; }
  __syncthreads();

  const u16* pA[4]; const u16* pB[4]; const u16* pC[4];
#pragma unroll
  for (int i = 0; i < 4; ++i) {
    int r = i * 32 + (tid >> 3);
    int g = (tid & 7) ^ (r & 7);
    pA[i] = xn + (size_t)stok[r] * D_ + g * 8;
    pB[i] = w1t + ((size_t)e * DFF_ + n0 + r) * D_ + g * 8;
    pC[i] = w2t + ((size_t)se * DFF_ + n0 + r) * D_ + g * 8;
  }
  f32x4 a1[4][4], a2[4][4];
#pragma unroll
  for (int mi = 0; mi < 4; ++mi)
#pragma unroll
    for (int ni = 0; ni < 4; ++ni) {
      a1[mi][ni] = (f32x4){0.f, 0.f, 0.f, 0.f};
      a2[mi][ni] = (f32x4){0.f, 0.f, 0.f, 0.f};
    }

  for (int kk = 0; kk < D_; kk += 64) {
    if (kk) __syncthreads();
#pragma unroll
    for (int i = 0; i < 4; ++i) {
      gload16(pA[i], As + i * 2048 + wid * 512);
      gload16(pB[i], Bs + i * 2048 + wid * 512);
      gload16(pC[i], Cs + i * 2048 + wid * 512);
      pA[i] += 64; pB[i] += 64; pC[i] += 64;
    }
    __syncthreads();
#pragma unroll
    for (int ks = 0; ks < 2; ++ks) {
      int slot = ((ks * 4) + (lane >> 4)) ^ (lane & 7);
      bf16x8 af[4], bfr[4], cfr[4];
#pragma unroll
      for (int mi = 0; mi < 4; ++mi)
        af[mi] = *(const bf16x8*)(As + (wm * 64 + mi * 16 + (lane & 15)) * 64 + slot * 8);
#pragma unroll
      for (int ni = 0; ni < 4; ++ni) {
        bfr[ni] = *(const bf16x8*)(Bs + (wn * 64 + ni * 16 + (lane & 15)) * 64 + slot * 8);
        cfr[ni] = *(const bf16x8*)(Cs + (wn * 64 + ni * 16 + (lane & 15)) * 64 + slot * 8);
      }
#pragma unroll
      for (int mi = 0; mi < 4; ++mi)
#pragma unroll
        for (int ni = 0; ni < 4; ++ni) {
          a1[mi][ni] = __builtin_amdgcn_mfma_f32_16x16x32_bf16(af[mi], bfr[ni], a1[mi][ni], 0, 0, 0);
          a2[mi][ni] = __builtin_amdgcn_mfma_f32_16x16x32_bf16(af[mi], cfr[ni], a2[mi][ni], 0, 0, 0);
        }
    }
  }
  int quad = lane >> 4;
#pragma unroll
  for (int ni = 0; ni < 4; ++ni) {
    int col = n0 + wn * 64 + ni * 16 + (lane & 15);
    float b1 = bias1[(size_t)e * DFF_ + col];
    float b2 = bias2[(size_t)se * DFF_ + col];
#pragma unroll
    for (int mi = 0; mi < 4; ++mi) {
      int rowb = mtile * 128 + wm * 64 + mi * 16 + quad * 4;
#pragma unroll
      for (int r = 0; r < 4; ++r) {
        float c1 = a1[mi][ni][r] + b1;
        float c2 = a2[mi][ni][r] + b2;
        float sig = 1.f / (1.f + expf(-c2));
        float v = (c2 * sig) * c2 * c1;
        h[(size_t)(rowb + r) * DFF_ + col] = f2bf(v);
      }
    }
  }
}

// ---------------- GEMM2: y = h @ w3[e]  (w3t is [E][D][DFF], k=f contiguous)
// 128x256 tile: halves the number of n-passes over h (A re-fetch 8->4),
// doubles MFMA per staged byte. acc[4][8], LDS 48KB, 2 blocks/CU.
__global__ __launch_bounds__(256, 2)
void gemm2(const u16* __restrict__ h, const u16* __restrict__ w3t,
           const int* __restrict__ tile_expert, u16* __restrict__ y) {
  int mtile = blockIdx.y;
  int e = tile_expert[mtile];
  if (e < 0) return;
  int n0 = blockIdx.x * 256;
  int tid = threadIdx.x;
  int lane = tid & 63, wid = tid >> 6;
  int wm = wid & 1, wn = wid >> 1;  // wn in {0,1}: 128-col half of 256

  __shared__ u16 As[128 * 64], Bs[256 * 64];

  const u16* pA[4]; const u16* pB[8];
#pragma unroll
  for (int i = 0; i < 4; ++i) {
    int r = i * 32 + (tid >> 3);
    int g = (tid & 7) ^ (r & 7);
    pA[i] = h + (size_t)(mtile * 128 + r) * DFF_ + g * 8;
  }
#pragma unroll
  for (int i = 0; i < 8; ++i) {
    int r = i * 32 + (tid >> 3);
    int g = (tid & 7) ^ (r & 7);
    pB[i] = w3t + ((size_t)e * D_ + n0 + r) * DFF_ + g * 8;
  }
  f32x4 acc[4][8];
#pragma unroll
  for (int mi = 0; mi < 4; ++mi)
#pragma unroll
    for (int ni = 0; ni < 8; ++ni) acc[mi][ni] = (f32x4){0.f, 0.f, 0.f, 0.f};

  for (int kk = 0; kk < DFF_; kk += 64) {
    if (kk) __syncthreads();
#pragma unroll
    for (int i = 0; i < 4; ++i) {
      gload16(pA[i], As + i * 2048 + wid * 512);
      pA[i] += 64;
    }
#pragma unroll
    for (int i = 0; i < 8; ++i) {
      gload16(pB[i], Bs + i * 2048 + wid * 512);
      pB[i] += 64;
    }
    __syncthreads();
#pragma unroll
    for (int ks = 0; ks < 2; ++ks) {
      int slot = ((ks * 4) + (lane >> 4)) ^ (lane & 7);
      bf16x8 af[4], bfr[8];
#pragma unroll
      for (int mi = 0; mi < 4; ++mi)
        af[mi] = *(const bf16x8*)(As + (wm * 64 + mi * 16 + (lane & 15)) * 64 + slot * 8);
#pragma unroll
      for (int ni = 0; ni < 8; ++ni)
        bfr[ni] = *(const bf16x8*)(Bs + (wn * 128 + ni * 16 + (lane & 15)) * 64 + slot * 8);
#pragma unroll
      for (int mi = 0; mi < 4; ++mi)
#pragma unroll
        for (int ni = 0; ni < 8; ++ni)
          acc[mi][ni] = __builtin_amdgcn_mfma_f32_16x16x32_bf16(af[mi], bfr[ni], acc[mi][ni], 0, 0, 0);
    }
  }
  int quad = lane >> 4;
#pragma unroll
  for (int ni = 0; ni < 8; ++ni) {
    int col = n0 + wn * 128 + ni * 16 + (lane & 15);
#pragma unroll
    for (int mi = 0; mi < 4; ++mi) {
      int rowb = mtile * 128 + wm * 64 + mi * 16 + quad * 4;
#pragma unroll
      for (int r = 0; r < 4; ++r)
        y[(size_t)(rowb + r) * D_ + col] = f2bf(acc[mi][ni][r]);
    }
  }
}

// ---------------- final: r_k = x + y_k ; LN2 each ; combine ; cluster LN
__global__ __launch_bounds__(256)
void k_final(const float* __restrict__ x, const float* __restrict__ wf,
             const int* __restrict__ idx, const int* __restrict__ rowmap,
             const u16* __restrict__ y, const float* __restrict__ ln2w,
             const float* __restrict__ ln2b, const float* __restrict__ clw,
             const float* __restrict__ clb, float* __restrict__ out) {
  __shared__ float2 sm[4];
  int t = blockIdx.x, tid = threadIdx.x;
  int r0 = rowmap[t * 2], r1 = rowmap[t * 2 + 1];
  int e0 = idx[t * 2], e1 = idx[t * 2 + 1];
  float w0 = wf[t * 2], w1v = wf[t * 2 + 1];
  const float* xr = x + (size_t)t * D_;
  const u16* y0 = y + (size_t)r0 * D_;
  const u16* y1 = y + (size_t)r1 * D_;
  float a[4], b[4];
  float s = 0.f, q = 0.f, s2 = 0.f, q2 = 0.f;
#pragma unroll
  for (int j = 0; j < 4; ++j) {
    int d = tid + j * 256;
    float xv = xr[d];
    a[j] = xv + bf2f(y0[d]);
    b[j] = xv + bf2f(y1[d]);
    s += a[j]; q += a[j] * a[j];
    s2 += b[j]; q2 += b[j] * b[j];
  }
  float m0, v0, m1, v1;
  blockmv(s, q, sm, tid, m0, v0);
  blockmv(s2, q2, sm, tid, m1, v1);
  float rs0 = rsqrtf(v0 + LN_EPS), rs1 = rsqrtf(v1 + LN_EPS);
  float c[4];
  s = 0.f; q = 0.f;
#pragma unroll
  for (int j = 0; j < 4; ++j) {
    int d = tid + j * 256;
    float n0v = (a[j] - m0) * rs0 * ln2w[(size_t)e0 * D_ + d] + ln2b[(size_t)e0 * D_ + d];
    float n1v = (b[j] - m1) * rs1 * ln2w[(size_t)e1 * D_ + d] + ln2b[(size_t)e1 * D_ + d];
    c[j] = w0 * n0v + w1v * n1v;
    s += c[j]; q += c[j] * c[j];
  }
  float m2, v2;
  blockmv(s, q, sm, tid, m2, v2);
  float rs2 = rsqrtf(v2 + LN_EPS);
#pragma unroll
  for (int j = 0; j < 4; ++j) {
    int d = tid + j * 256;
    out[(size_t)t * D_ + d] = (c[j] - m2) * rs2 * clw[d] + clb[d];
  }
}

extern "C" void kernel_launch(void* const* d_in, const int* in_sizes, int n_in,
                              void* d_out, int out_size, void* d_ws, size_t ws_size,
                              hipStream_t stream) {
  const float* x    = (const float*)d_in[0];
  const float* ew   = (const float*)d_in[1];
  const int*   idx  = (const int*)d_in[2];
  const float* ln1w = (const float*)d_in[3];
  const float* ln1b = (const float*)d_in[4];
  const float* w1   = (const float*)d_in[5];
  const float* w2   = (const float*)d_in[6];
  const float* w3   = (const float*)d_in[7];
  const float* ln2w = (const float*)d_in[8];
  const float* ln2b = (const float*)d_in[9];
  const float* clw  = (const float*)d_in[10];
  const float* clb  = (const float*)d_in[11];
  const float* capu = (const float*)d_in[12];
  const float* cap  = (const float*)d_in[13];
  float* out = (float*)d_out;

  char* w = (char*)d_ws;
  size_t off = 0;
  auto alloc = [&](size_t b) { size_t cur = off; off += (b + 255) & ~(size_t)255; return (void*)(w + cur); };

  u16* xn   = (u16*)alloc((size_t)NTOK * D_ * 2);
  u16* w1t  = (u16*)alloc((size_t)E_ * DFF_ * D_ * 2);
  u16* w2t  = (u16*)alloc((size_t)3 * DFF_ * D_ * 2);
  u16* w3t  = (u16*)alloc((size_t)E_ * D_ * DFF_ * 2);
  float* bias1 = (float*)alloc((size_t)E_ * DFF_ * 4);
  float* bias2 = (float*)alloc((size_t)3 * DFF_ * 4);
  u16* h    = (u16*)alloc((size_t)MAXROWS * DFF_ * 2);
  u16* y    = (u16*)alloc((size_t)MAXROWS * D_ * 2);
  float* wf = (float*)alloc((size_t)NTOK * 2 * 4);
  int* rowmap      = (int*)alloc((size_t)NA * 4);
  int* tok_of_row  = (int*)alloc((size_t)MAXROWS * 4);
  int* cnt         = (int*)alloc(E_ * 4);
  int* cnt2        = (int*)alloc(E_ * 4);
  int* offs        = (int*)alloc((E_ + 1) * 4);
  int* tile_expert = (int*)alloc(MAXTILES * 4);

  hipMemsetAsync(bias1, 0, (size_t)E_ * DFF_ * 4, stream);
  hipMemsetAsync(bias2, 0, (size_t)3 * DFF_ * 4, stream);
  hipMemsetAsync(cnt, 0, E_ * 4, stream);
  hipMemsetAsync(cnt2, 0, E_ * 4, stream);
  hipMemsetAsync(tok_of_row, 0xFF, (size_t)MAXROWS * 4, stream);
  hipMemsetAsync(tile_expert, 0xFF, MAXTILES * 4, stream);

  k_stats<<<NTOK, 256, 0, stream>>>(x, ew, idx, capu, cap, xn, wf, cnt);
  k_scan<<<1, 64, 0, stream>>>(cnt, offs, tile_expert);
  k_assign<<<NA / 256, 256, 0, stream>>>(idx, offs, cnt2, rowmap, tok_of_row);

  // w1: [E][D][DFF] -> w1t [E][DFF][D], scale ln1_w, bias1 += ln1_b^T w1
  k_convert<<<dim3(DFF_ / 64, D_ / 64, E_), 256, 0, stream>>>(w1, ln1w, ln1b, w1t, bias1, D_, DFF_, 1);
  // w2: swiglu experts 0,3,6 -> compact slots 0,1,2
  k_convert<<<dim3(DFF_ / 64, D_ / 64, 3), 256, 0, stream>>>(w2, ln1w, ln1b, w2t, bias2, D_, DFF_, 3);
  // w3: [E][DFF][D] -> w3t [E][D][DFF], no scale/bias
  k_convert<<<dim3(D_ / 64, DFF_ / 64, E_), 256, 0, stream>>>(w3, nullptr, nullptr, w3t, nullptr, DFF_, D_, 1);

  dim3 g1(DFF_ / 128, MAXTILES);
  gemm1_single<<<g1, 256, 0, stream>>>(xn, w1t, bias1, tok_of_row, tile_expert, h);
  gemm1_swiglu<<<g1, 256, 0, stream>>>(xn, w1t, w2t, bias1, bias2, tok_of_row, tile_expert, h);

  dim3 g2(D_ / 256, MAXTILES);
  gemm2<<<g2, 256, 0, stream>>>(h, w3t, tile_expert, y);

  k_final<<<NTOK, 256, 0, stream>>>(x, wf, idx, rowmap, y, ln2w, ln2b, clw, clb, out);
}

// Round 4
// 1131.773 us; speedup vs baseline: 1.0553x; 1.0553x over previous
//
#include <hip/hip_runtime.h>
#include <stdint.h>

typedef unsigned short u16;
typedef __attribute__((ext_vector_type(8))) short bf16x8;
typedef __attribute__((ext_vector_type(4))) float f32x4;

#define E_ 8
#define D_ 1024
#define DFF_ 4096
#define NTOK 8192
#define NA 16384
#define MAXROWS 17408
#define MAXTILES 136
#define LN_EPS 1e-5f

__device__ __forceinline__ u16 f2bf(float f) {
  union { float f; uint32_t u; } a; a.f = f;
  uint32_t r = a.u + 0x7FFFu + ((a.u >> 16) & 1u);
  return (u16)(r >> 16);
}
__device__ __forceinline__ float bf2f(u16 h) {
  union { uint32_t u; float f; } a; a.u = ((uint32_t)h) << 16; return a.f;
}

__device__ __forceinline__ void gload16(const void* g, void* l) {
  __builtin_amdgcn_global_load_lds((const __attribute__((address_space(1))) void*)g,
                                   (__attribute__((address_space(3))) void*)l, 16, 0, 0);
}

// block-wide mean/var over 1024 elements (256 threads x 4 each)
__device__ __forceinline__ void blockmv(float s, float q, float2* sm, int tid,
                                        float& mean, float& var) {
#pragma unroll
  for (int o = 32; o > 0; o >>= 1) {
    s += __shfl_xor(s, o, 64);
    q += __shfl_xor(q, o, 64);
  }
  if ((tid & 63) == 0) sm[tid >> 6] = make_float2(s, q);
  __syncthreads();
  if (tid == 0) {
    float ts = 0.f, tq = 0.f;
#pragma unroll
    for (int i = 0; i < 4; ++i) { ts += sm[i].x; tq += sm[i].y; }
    sm[0] = make_float2(ts, tq);
  }
  __syncthreads();
  mean = sm[0].x * (1.f / 1024.f);
  var  = sm[0].y * (1.f / 1024.f) - mean * mean;
  __syncthreads();
}

// ---------------- kernel 1: per-token stats, x_norm bf16, routing weights, counts
__global__ __launch_bounds__(256)
void k_stats(const float* __restrict__ x, const float* __restrict__ ew,
             const int* __restrict__ idx, const float* __restrict__ capu,
             const float* __restrict__ cap, u16* __restrict__ xn,
             float* __restrict__ wf, int* __restrict__ cnt) {
  __shared__ float2 sm[4];
  int t = blockIdx.x, tid = threadIdx.x;
  const float* xr = x + (size_t)t * D_;
  float v[4]; float s = 0.f, q = 0.f;
#pragma unroll
  for (int j = 0; j < 4; ++j) {
    v[j] = xr[tid + j * 256];
    s += v[j]; q += v[j] * v[j];
  }
  float m, var;
  blockmv(s, q, sm, tid, m, var);
  float rs = rsqrtf(var + LN_EPS);
#pragma unroll
  for (int j = 0; j < 4; ++j)
    xn[(size_t)t * D_ + tid + j * 256] = f2bf((v[j] - m) * rs);
  if (tid == 0) {
    float pw[2];
#pragma unroll
    for (int k = 0; k < 2; ++k) {
      int e = idx[t * 2 + k];
      float pen = capu[e] / (cap[e] + 1e-8f);
      pen = fminf(fmaxf(pen, 0.f), 2.f);
      pw[k] = ew[t * 2 + k] / (1.f + pen);
      atomicAdd(&cnt[e], 1);
    }
    float mx = fmaxf(pw[0], pw[1]);
    float z0 = expf(pw[0] - mx), z1 = expf(pw[1] - mx);
    float inv = 1.f / (z0 + z1);
    wf[t * 2] = z0 * inv; wf[t * 2 + 1] = z1 * inv;
  }
}

// ---------------- kernel 2: scan padded counts, tile->expert map
__global__ void k_scan(const int* __restrict__ cnt, int* __restrict__ offs,
                       int* __restrict__ tile_expert) {
  if (threadIdx.x == 0 && blockIdx.x == 0) {
    int o = 0;
    for (int e = 0; e < E_; ++e) {
      offs[e] = o;
      int p = (cnt[e] + 127) & ~127;
      for (int mtl = 0; mtl < (p >> 7); ++mtl) tile_expert[(o >> 7) + mtl] = e;
      o += p;
    }
    offs[E_] = o;
  }
}

// ---------------- kernel 3: assign rows
__global__ __launch_bounds__(256)
void k_assign(const int* __restrict__ idx, const int* __restrict__ offs,
              int* __restrict__ cnt2, int* __restrict__ rowmap,
              int* __restrict__ tok_of_row) {
  int i = blockIdx.x * 256 + threadIdx.x;
  if (i >= NA) return;
  int e = idx[i];
  int pos = atomicAdd(&cnt2[e], 1);
  int row = offs[e] + pos;
  rowmap[i] = row;
  tok_of_row[row] = i >> 1;
}

// ---------------- kernel 4: transpose+convert weights fp32->bf16, fold ln1_w, bias partials
// src [nmat][R][C] (expert stride e_step in source), dst [z][C][R]
// Vectorized: float4 loads (16B/lane), ushort4 stores (8B/lane).
__global__ __launch_bounds__(256)
void k_convert(const float* __restrict__ src, const float* __restrict__ lnw,
               const float* __restrict__ lnb, u16* __restrict__ dst,
               float* __restrict__ bias, int R, int C, int e_step) {
  __shared__ float tbuf[64][65];
  int z = blockIdx.z;
  int es = z * e_step;
  const float* s = src + (size_t)es * R * C;
  u16* dz = dst + (size_t)z * R * C;
  int r0 = blockIdx.y * 64, c0 = blockIdx.x * 64;
  int tid = threadIdx.x;
  // load: 4 passes; lane covers 4 consecutive cols (float4), 16 rows/pass
  int lr = tid >> 4;          // 0..15
  int lc4 = (tid & 15) * 4;   // 0,4,..,60
#pragma unroll
  for (int p = 0; p < 4; ++p) {
    int r = lr + p * 16;
    const float4 v = *(const float4*)&s[(size_t)(r0 + r) * C + (c0 + lc4)];
    tbuf[r][lc4 + 0] = v.x; tbuf[r][lc4 + 1] = v.y;
    tbuf[r][lc4 + 2] = v.z; tbuf[r][lc4 + 3] = v.w;
  }
  __syncthreads();
  if (bias != nullptr && tid < 64) {
    float acc = 0.f;
    const float* lb = lnb + (size_t)es * R;
#pragma unroll 8
    for (int r2 = 0; r2 < 64; ++r2) acc += lb[r0 + r2] * tbuf[r2][tid];
    atomicAdd(&bias[(size_t)z * C + c0 + tid], acc);
  }
  // write: lane owns fixed out-row (c) and 4 consecutive out-cols (r) -> ushort4
  int cw = tid >> 4;          // 0..15 (+16*p)
  int r4 = (tid & 15) * 4;    // 0,4,..,60
  float sv[4];
#pragma unroll
  for (int j = 0; j < 4; ++j)
    sv[j] = (lnw != nullptr) ? lnw[(size_t)es * R + r0 + r4 + j] : 1.f;
#pragma unroll
  for (int p = 0; p < 4; ++p) {
    int c = cw + p * 16;
    u16 o0 = f2bf(tbuf[r4 + 0][c] * sv[0]);
    u16 o1 = f2bf(tbuf[r4 + 1][c] * sv[1]);
    u16 o2 = f2bf(tbuf[r4 + 2][c] * sv[2]);
    u16 o3 = f2bf(tbuf[r4 + 3][c] * sv[3]);
    *(ushort4*)&dz[(size_t)(c0 + c) * R + (r0 + r4)] = make_ushort4(o0, o1, o2, o3);
  }
}

// ---------------- GEMM1, gelu/relu experts: h = act(x_norm @ w1t[e]^T + bias1[e])
__global__ __launch_bounds__(256, 3)
void gemm1_single(const u16* __restrict__ xn, const u16* __restrict__ w1t,
                  const float* __restrict__ bias1, const int* __restrict__ tok_of_row,
                  const int* __restrict__ tile_expert, u16* __restrict__ h) {
  int mtile = blockIdx.y;
  int e = tile_expert[mtile];
  if (e < 0 || (e % 3) == 0) return;
  int act = e % 3;  // 1=gelu, 2=relu
  int n0 = blockIdx.x * 128;
  int tid = threadIdx.x;
  int lane = tid & 63, wid = tid >> 6;
  int wm = wid & 1, wn = wid >> 1;

  __shared__ u16 As[128 * 64], Bs[128 * 64];
  __shared__ int stok[128];
  if (tid < 128) { int t = tok_of_row[mtile * 128 + tid]; stok[tid] = t < 0 ? 0 : t; }
  __syncthreads();

  const u16* pA[4]; const u16* pB[4];
#pragma unroll
  for (int i = 0; i < 4; ++i) {
    int r = i * 32 + (tid >> 3);
    int g = (tid & 7) ^ (r & 7);
    pA[i] = xn + (size_t)stok[r] * D_ + g * 8;
    pB[i] = w1t + ((size_t)e * DFF_ + n0 + r) * D_ + g * 8;
  }
  f32x4 acc[4][4];
#pragma unroll
  for (int mi = 0; mi < 4; ++mi)
#pragma unroll
    for (int ni = 0; ni < 4; ++ni) acc[mi][ni] = (f32x4){0.f, 0.f, 0.f, 0.f};

  for (int kk = 0; kk < D_; kk += 64) {
    if (kk) __syncthreads();
#pragma unroll
    for (int i = 0; i < 4; ++i) {
      gload16(pA[i], As + i * 2048 + wid * 512);
      gload16(pB[i], Bs + i * 2048 + wid * 512);
      pA[i] += 64; pB[i] += 64;
    }
    __syncthreads();
#pragma unroll
    for (int ks = 0; ks < 2; ++ks) {
      int slot = ((ks * 4) + (lane >> 4)) ^ (lane & 7);
      bf16x8 af[4], bfr[4];
#pragma unroll
      for (int mi = 0; mi < 4; ++mi)
        af[mi] = *(const bf16x8*)(As + (wm * 64 + mi * 16 + (lane & 15)) * 64 + slot * 8);
#pragma unroll
      for (int ni = 0; ni < 4; ++ni)
        bfr[ni] = *(const bf16x8*)(Bs + (wn * 64 + ni * 16 + (lane & 15)) * 64 + slot * 8);
#pragma unroll
      for (int mi = 0; mi < 4; ++mi)
#pragma unroll
        for (int ni = 0; ni < 4; ++ni)
          acc[mi][ni] = __builtin_amdgcn_mfma_f32_16x16x32_bf16(af[mi], bfr[ni], acc[mi][ni], 0, 0, 0);
    }
  }
  int quad = lane >> 4;
#pragma unroll
  for (int ni = 0; ni < 4; ++ni) {
    int col = n0 + wn * 64 + ni * 16 + (lane & 15);
    float b1 = bias1[(size_t)e * DFF_ + col];
#pragma unroll
    for (int mi = 0; mi < 4; ++mi) {
      int rowb = mtile * 128 + wm * 64 + mi * 16 + quad * 4;
#pragma unroll
      for (int r = 0; r < 4; ++r) {
        float v = acc[mi][ni][r] + b1;
        if (act == 1) v = 0.5f * v * (1.f + erff(v * 0.70710678118f));
        else v = fmaxf(v, 0.f);
        h[(size_t)(rowb + r) * DFF_ + col] = f2bf(v);
      }
    }
  }
}

// ---------------- GEMM1, swiglu experts: dual accumulate h1,h2; h = silu(h2)*h2*h1
__global__ __launch_bounds__(256, 2)
void gemm1_swiglu(const u16* __restrict__ xn, const u16* __restrict__ w1t,
                  const u16* __restrict__ w2t, const float* __restrict__ bias1,
                  const float* __restrict__ bias2, const int* __restrict__ tok_of_row,
                  const int* __restrict__ tile_expert, u16* __restrict__ h) {
  int mtile = blockIdx.y;
  int e = tile_expert[mtile];
  if (e < 0 || (e % 3) != 0) return;
  int se = e / 3;
  int n0 = blockIdx.x * 128;
  int tid = threadIdx.x;
  int lane = tid & 63, wid = tid >> 6;
  int wm = wid & 1, wn = wid >> 1;

  __shared__ u16 As[128 * 64], Bs[128 * 64], Cs[128 * 64];
  __shared__ int stok[128];
  if (tid < 128) { int t = tok_of_row[mtile * 128 + tid]; stok[tid] = t < 0 ? 0 : t; }
  __syncthreads();

  const u16* pA[4]; const u16* pB[4]; const u16* pC[4];
#pragma unroll
  for (int i = 0; i < 4; ++i) {
    int r = i * 32 + (tid >> 3);
    int g = (tid & 7) ^ (r & 7);
    pA[i] = xn + (size_t)stok[r] * D_ + g * 8;
    pB[i] = w1t + ((size_t)e * DFF_ + n0 + r) * D_ + g * 8;
    pC[i] = w2t + ((size_t)se * DFF_ + n0 + r) * D_ + g * 8;
  }
  f32x4 a1[4][4], a2[4][4];
#pragma unroll
  for (int mi = 0; mi < 4; ++mi)
#pragma unroll
    for (int ni = 0; ni < 4; ++ni) {
      a1[mi][ni] = (f32x4){0.f, 0.f, 0.f, 0.f};
      a2[mi][ni] = (f32x4){0.f, 0.f, 0.f, 0.f};
    }

  for (int kk = 0; kk < D_; kk += 64) {
    if (kk) __syncthreads();
#pragma unroll
    for (int i = 0; i < 4; ++i) {
      gload16(pA[i], As + i * 2048 + wid * 512);
      gload16(pB[i], Bs + i * 2048 + wid * 512);
      gload16(pC[i], Cs + i * 2048 + wid * 512);
      pA[i] += 64; pB[i] += 64; pC[i] += 64;
    }
    __syncthreads();
#pragma unroll
    for (int ks = 0; ks < 2; ++ks) {
      int slot = ((ks * 4) + (lane >> 4)) ^ (lane & 7);
      bf16x8 af[4], bfr[4], cfr[4];
#pragma unroll
      for (int mi = 0; mi < 4; ++mi)
        af[mi] = *(const bf16x8*)(As + (wm * 64 + mi * 16 + (lane & 15)) * 64 + slot * 8);
#pragma unroll
      for (int ni = 0; ni < 4; ++ni) {
        bfr[ni] = *(const bf16x8*)(Bs + (wn * 64 + ni * 16 + (lane & 15)) * 64 + slot * 8);
        cfr[ni] = *(const bf16x8*)(Cs + (wn * 64 + ni * 16 + (lane & 15)) * 64 + slot * 8);
      }
#pragma unroll
      for (int mi = 0; mi < 4; ++mi)
#pragma unroll
        for (int ni = 0; ni < 4; ++ni) {
          a1[mi][ni] = __builtin_amdgcn_mfma_f32_16x16x32_bf16(af[mi], bfr[ni], a1[mi][ni], 0, 0, 0);
          a2[mi][ni] = __builtin_amdgcn_mfma_f32_16x16x32_bf16(af[mi], cfr[ni], a2[mi][ni], 0, 0, 0);
        }
    }
  }
  int quad = lane >> 4;
#pragma unroll
  for (int ni = 0; ni < 4; ++ni) {
    int col = n0 + wn * 64 + ni * 16 + (lane & 15);
    float b1 = bias1[(size_t)e * DFF_ + col];
    float b2 = bias2[(size_t)se * DFF_ + col];
#pragma unroll
    for (int mi = 0; mi < 4; ++mi) {
      int rowb = mtile * 128 + wm * 64 + mi * 16 + quad * 4;
#pragma unroll
      for (int r = 0; r < 4; ++r) {
        float c1 = a1[mi][ni][r] + b1;
        float c2 = a2[mi][ni][r] + b2;
        float sig = 1.f / (1.f + expf(-c2));
        float v = (c2 * sig) * c2 * c1;
        h[(size_t)(rowb + r) * DFF_ + col] = f2bf(v);
      }
    }
  }
}

// ---------------- GEMM2: y = h @ w3[e]  (w3t is [E][D][DFF], k=f contiguous)
// 128x128 tile (occupancy 2 blocks/CU) + chunked XCD swizzle: each XCD owns
// a contiguous run of m-tiles x all 8 n-tiles, so each h-panel (1MB) is
// fetched by exactly one XCD's L2 instead of all 8.
__global__ __launch_bounds__(256, 2)
void gemm2(const u16* __restrict__ h, const u16* __restrict__ w3t,
           const int* __restrict__ tile_expert, u16* __restrict__ y) {
  // chunked XCD swizzle (nwg = 8*136 = 1088, %8 == 0 -> simple form bijective)
  int lin = blockIdx.y * gridDim.x + blockIdx.x;
  int cpx = (gridDim.x * gridDim.y) >> 3;
  int swz = (lin & 7) * cpx + (lin >> 3);
  int mtile = swz >> 3;            // gridDim.x == 8
  int n0 = (swz & 7) * 128;
  int e = tile_expert[mtile];
  if (e < 0) return;
  int tid = threadIdx.x;
  int lane = tid & 63, wid = tid >> 6;
  int wm = wid & 1, wn = wid >> 1;

  __shared__ u16 As[128 * 64], Bs[128 * 64];

  const u16* pA[4]; const u16* pB[4];
#pragma unroll
  for (int i = 0; i < 4; ++i) {
    int r = i * 32 + (tid >> 3);
    int g = (tid & 7) ^ (r & 7);
    pA[i] = h + (size_t)(mtile * 128 + r) * DFF_ + g * 8;
    pB[i] = w3t + ((size_t)e * D_ + n0 + r) * DFF_ + g * 8;
  }
  f32x4 acc[4][4];
#pragma unroll
  for (int mi = 0; mi < 4; ++mi)
#pragma unroll
    for (int ni = 0; ni < 4; ++ni) acc[mi][ni] = (f32x4){0.f, 0.f, 0.f, 0.f};

  for (int kk = 0; kk < DFF_; kk += 64) {
    if (kk) __syncthreads();
#pragma unroll
    for (int i = 0; i < 4; ++i) {
      gload16(pA[i], As + i * 2048 + wid * 512);
      gload16(pB[i], Bs + i * 2048 + wid * 512);
      pA[i] += 64; pB[i] += 64;
    }
    __syncthreads();
#pragma unroll
    for (int ks = 0; ks < 2; ++ks) {
      int slot = ((ks * 4) + (lane >> 4)) ^ (lane & 7);
      bf16x8 af[4], bfr[4];
#pragma unroll
      for (int mi = 0; mi < 4; ++mi)
        af[mi] = *(const bf16x8*)(As + (wm * 64 + mi * 16 + (lane & 15)) * 64 + slot * 8);
#pragma unroll
      for (int ni = 0; ni < 4; ++ni)
        bfr[ni] = *(const bf16x8*)(Bs + (wn * 64 + ni * 16 + (lane & 15)) * 64 + slot * 8);
#pragma unroll
      for (int mi = 0; mi < 4; ++mi)
#pragma unroll
        for (int ni = 0; ni < 4; ++ni)
          acc[mi][ni] = __builtin_amdgcn_mfma_f32_16x16x32_bf16(af[mi], bfr[ni], acc[mi][ni], 0, 0, 0);
    }
  }
  int quad = lane >> 4;
#pragma unroll
  for (int ni = 0; ni < 4; ++ni) {
    int col = n0 + wn * 64 + ni * 16 + (lane & 15);
#pragma unroll
    for (int mi = 0; mi < 4; ++mi) {
      int rowb = mtile * 128 + wm * 64 + mi * 16 + quad * 4;
#pragma unroll
      for (int r = 0; r < 4; ++r)
        y[(size_t)(rowb + r) * D_ + col] = f2bf(acc[mi][ni][r]);
    }
  }
}

// ---------------- final: r_k = x + y_k ; LN2 each ; combine ; cluster LN
__global__ __launch_bounds__(256)
void k_final(const float* __restrict__ x, const float* __restrict__ wf,
             const int* __restrict__ idx, const int* __restrict__ rowmap,
             const u16* __restrict__ y, const float* __restrict__ ln2w,
             const float* __restrict__ ln2b, const float* __restrict__ clw,
             const float* __restrict__ clb, float* __restrict__ out) {
  __shared__ float2 sm[4];
  int t = blockIdx.x, tid = threadIdx.x;
  int r0 = rowmap[t * 2], r1 = rowmap[t * 2 + 1];
  int e0 = idx[t * 2], e1 = idx[t * 2 + 1];
  float w0 = wf[t * 2], w1v = wf[t * 2 + 1];
  const float* xr = x + (size_t)t * D_;
  const u16* y0 = y + (size_t)r0 * D_;
  const u16* y1 = y + (size_t)r1 * D_;
  float a[4], b[4];
  float s = 0.f, q = 0.f, s2 = 0.f, q2 = 0.f;
#pragma unroll
  for (int j = 0; j < 4; ++j) {
    int d = tid + j * 256;
    float xv = xr[d];
    a[j] = xv + bf2f(y0[d]);
    b[j] = xv + bf2f(y1[d]);
    s += a[j]; q += a[j] * a[j];
    s2 += b[j]; q2 += b[j] * b[j];
  }
  float m0, v0, m1, v1;
  blockmv(s, q, sm, tid, m0, v0);
  blockmv(s2, q2, sm, tid, m1, v1);
  float rs0 = rsqrtf(v0 + LN_EPS), rs1 = rsqrtf(v1 + LN_EPS);
  float c[4];
  s = 0.f; q = 0.f;
#pragma unroll
  for (int j = 0; j < 4; ++j) {
    int d = tid + j * 256;
    float n0v = (a[j] - m0) * rs0 * ln2w[(size_t)e0 * D_ + d] + ln2b[(size_t)e0 * D_ + d];
    float n1v = (b[j] - m1) * rs1 * ln2w[(size_t)e1 * D_ + d] + ln2b[(size_t)e1 * D_ + d];
    c[j] = w0 * n0v + w1v * n1v;
    s += c[j]; q += c[j] * c[j];
  }
  float m2, v2;
  blockmv(s, q, sm, tid, m2, v2);
  float rs2 = rsqrtf(v2 + LN_EPS);
#pragma unroll
  for (int j = 0; j < 4; ++j) {
    int d = tid + j * 256;
    out[(size_t)t * D_ + d] = (c[j] - m2) * rs2 * clw[d] + clb[d];
  }
}

extern "C" void kernel_launch(void* const* d_in, const int* in_sizes, int n_in,
                              void* d_out, int out_size, void* d_ws, size_t ws_size,
                              hipStream_t stream) {
  const float* x    = (const float*)d_in[0];
  const float* ew   = (const float*)d_in[1];
  const int*   idx  = (const int*)d_in[2];
  const float* ln1w = (const float*)d_in[3];
  const float* ln1b = (const float*)d_in[4];
  const float* w1   = (const float*)d_in[5];
  const float* w2   = (const float*)d_in[6];
  const float* w3   = (const float*)d_in[7];
  const float* ln2w = (const float*)d_in[8];
  const float* ln2b = (const float*)d_in[9];
  const float* clw  = (const float*)d_in[10];
  const float* clb  = (const float*)d_in[11];
  const float* capu = (const float*)d_in[12];
  const float* cap  = (const float*)d_in[13];
  float* out = (float*)d_out;

  char* w = (char*)d_ws;
  size_t off = 0;
  auto alloc = [&](size_t b) { size_t cur = off; off += (b + 255) & ~(size_t)255; return (void*)(w + cur); };

  u16* xn   = (u16*)alloc((size_t)NTOK * D_ * 2);
  u16* w1t  = (u16*)alloc((size_t)E_ * DFF_ * D_ * 2);
  u16* w2t  = (u16*)alloc((size_t)3 * DFF_ * D_ * 2);
  u16* w3t  = (u16*)alloc((size_t)E_ * D_ * DFF_ * 2);
  float* bias1 = (float*)alloc((size_t)E_ * DFF_ * 4);
  float* bias2 = (float*)alloc((size_t)3 * DFF_ * 4);
  u16* h    = (u16*)alloc((size_t)MAXROWS * DFF_ * 2);
  u16* y    = (u16*)alloc((size_t)MAXROWS * D_ * 2);
  float* wf = (float*)alloc((size_t)NTOK * 2 * 4);
  int* rowmap      = (int*)alloc((size_t)NA * 4);
  int* tok_of_row  = (int*)alloc((size_t)MAXROWS * 4);
  int* cnt         = (int*)alloc(E_ * 4);
  int* cnt2        = (int*)alloc(E_ * 4);
  int* offs        = (int*)alloc((E_ + 1) * 4);
  int* tile_expert = (int*)alloc(MAXTILES * 4);

  hipMemsetAsync(bias1, 0, (size_t)E_ * DFF_ * 4, stream);
  hipMemsetAsync(bias2, 0, (size_t)3 * DFF_ * 4, stream);
  hipMemsetAsync(cnt, 0, E_ * 4, stream);
  hipMemsetAsync(cnt2, 0, E_ * 4, stream);
  hipMemsetAsync(tok_of_row, 0xFF, (size_t)MAXROWS * 4, stream);
  hipMemsetAsync(tile_expert, 0xFF, MAXTILES * 4, stream);

  k_stats<<<NTOK, 256, 0, stream>>>(x, ew, idx, capu, cap, xn, wf, cnt);
  k_scan<<<1, 64, 0, stream>>>(cnt, offs, tile_expert);
  k_assign<<<NA / 256, 256, 0, stream>>>(idx, offs, cnt2, rowmap, tok_of_row);

  // w1: [E][D][DFF] -> w1t [E][DFF][D], scale ln1_w, bias1 += ln1_b^T w1
  k_convert<<<dim3(DFF_ / 64, D_ / 64, E_), 256, 0, stream>>>(w1, ln1w, ln1b, w1t, bias1, D_, DFF_, 1);
  // w2: swiglu experts 0,3,6 -> compact slots 0,1,2
  k_convert<<<dim3(DFF_ / 64, D_ / 64, 3), 256, 0, stream>>>(w2, ln1w, ln1b, w2t, bias2, D_, DFF_, 3);
  // w3: [E][DFF][D] -> w3t [E][D][DFF], no scale/bias
  k_convert<<<dim3(D_ / 64, DFF_ / 64, E_), 256, 0, stream>>>(w3, nullptr, nullptr, w3t, nullptr, DFF_, D_, 1);

  dim3 g1(DFF_ / 128, MAXTILES);
  gemm1_single<<<g1, 256, 0, stream>>>(xn, w1t, bias1, tok_of_row, tile_expert, h);
  gemm1_swiglu<<<g1, 256, 0, stream>>>(xn, w1t, w2t, bias1, bias2, tok_of_row, tile_expert, h);

  dim3 g2(D_ / 128, MAXTILES);
  gemm2<<<g2, 256, 0, stream>>>(h, w3t, tile_expert, y);

  k_final<<<NTOK, 256, 0, stream>>>(x, wf, idx, rowmap, y, ln2w, ln2b, clw, clb, out);
}